// Round 5
// baseline (13218.668 us; speedup 1.0000x reference)
//
#include <hip/hip_runtime.h>
#include <hip/hip_bf16.h>

#define S_LEN 2048
#define BATCH 64
#define HID   512
#define GATES 2048   // 4*HID
#define DIN   512

typedef __attribute__((ext_vector_type(8))) short short8v;
typedef __attribute__((ext_vector_type(4))) float f32x4;

__device__ inline unsigned short f2bf(float f) {
  union { float f; unsigned u; } a; a.f = f;
  unsigned r = a.u + 0x7fffu + ((a.u >> 16) & 1u);
  return (unsigned short)(r >> 16);
}
__device__ inline float bf2f(unsigned short h) {
  union { unsigned u; float f; } a; a.u = ((unsigned)h) << 16; return a.f;
}

// ---------- kernel 1: split x (fp32) -> bf16 hi + lo ----------
__global__ __launch_bounds__(256) void k_split_x(const float* __restrict__ x,
                                                 unsigned short* __restrict__ xhi,
                                                 unsigned short* __restrict__ xlo) {
  const long total = (long)S_LEN * BATCH * DIN / 4;
  long i = (long)blockIdx.x * blockDim.x + threadIdx.x;
  const long stride = (long)gridDim.x * blockDim.x;
  for (; i < total; i += stride) {
    float4 v = ((const float4*)x)[i];
    ushort4 hv, lv;
    hv.x = f2bf(v.x); lv.x = f2bf(v.x - bf2f(hv.x));
    hv.y = f2bf(v.y); lv.y = f2bf(v.y - bf2f(hv.y));
    hv.z = f2bf(v.z); lv.z = f2bf(v.z - bf2f(hv.z));
    hv.w = f2bf(v.w); lv.w = f2bf(v.w - bf2f(hv.w));
    ((ushort4*)xhi)[i] = hv;
    ((ushort4*)xlo)[i] = lv;
  }
}

// ---------- kernel 2: weights -> bf16, bias sum ----------
__global__ __launch_bounds__(256) void k_prep_w(const float* __restrict__ Wih,
                                                const float* __restrict__ Whh,
                                                const float* __restrict__ bih,
                                                const float* __restrict__ bhh,
                                                unsigned short* __restrict__ WihB,
                                                unsigned short* __restrict__ WhhB,
                                                float* __restrict__ bias) {
  int i = blockIdx.x * 256 + threadIdx.x;
  if (i < GATES * DIN) {
    WihB[i] = f2bf(Wih[i]);
    WhhB[i] = f2bf(Whh[i]);
  }
  if (i < GATES) bias[i] = bih[i] + bhh[i];
}

// ---------- kernel 3: pre[t][u][b][gate] = x[t,b,:]·Wih[gate*512+u,:] + biases ----------
#define BM 128
#define BN 128
#define BK 32
#define LDSROW 40

__global__ __launch_bounds__(256) void k_gemm_pre(
    const unsigned short* __restrict__ A,   // WihB [2048][512]
    const unsigned short* __restrict__ Bh,  // xhi  [131072][512]
    const unsigned short* __restrict__ Bl,  // xlo
    const float* __restrict__ bias,
    unsigned short* __restrict__ pre)       // [S][512 u][64 b][4 gate] bf16
{
  __shared__ unsigned short As [BM * LDSROW];
  __shared__ unsigned short Bhs[BM * LDSROW];
  __shared__ unsigned short Bls[BM * LDSROW];

  const int tid  = threadIdx.x;
  const int lane = tid & 63;
  const int wave = tid >> 6;
  const int bm = blockIdx.x & 15;
  const int bn = blockIdx.x >> 4;
  const int wr = wave >> 1, wc = wave & 1;

  f32x4 acc[4][4];
  #pragma unroll
  for (int i = 0; i < 4; ++i)
    #pragma unroll
    for (int j = 0; j < 4; ++j) acc[i][j] = (f32x4){0.f, 0.f, 0.f, 0.f};

  const long arow0 = (long)bm * BM;
  const long brow0 = (long)bn * BN;

  for (int kt = 0; kt < DIN / BK; ++kt) {
    #pragma unroll
    for (int it = 0; it < 2; ++it) {
      int c = tid + it * 256;
      int row = c >> 2, kc = c & 3;
      int lbyte = row * (LDSROW * 2) + kc * 16;
      long ga = (arow0 + row) * 512 + kt * BK + kc * 8;
      long gb = (brow0 + row) * 512 + kt * BK + kc * 8;
      *(short8v*)((char*)As  + lbyte) = *(const short8v*)(A  + ga);
      *(short8v*)((char*)Bhs + lbyte) = *(const short8v*)(Bh + gb);
      *(short8v*)((char*)Bls + lbyte) = *(const short8v*)(Bl + gb);
    }
    __syncthreads();

    short8v a[4], bh[4], bl[4];
    #pragma unroll
    for (int mt = 0; mt < 4; ++mt) {
      int r = wr * 64 + mt * 16 + (lane & 15);
      a[mt] = *(const short8v*)((const char*)As + r * (LDSROW * 2) + (lane >> 4) * 16);
    }
    #pragma unroll
    for (int nt = 0; nt < 4; ++nt) {
      int r = wc * 64 + nt * 16 + (lane & 15);
      bh[nt] = *(const short8v*)((const char*)Bhs + r * (LDSROW * 2) + (lane >> 4) * 16);
      bl[nt] = *(const short8v*)((const char*)Bls + r * (LDSROW * 2) + (lane >> 4) * 16);
    }
    #pragma unroll
    for (int mt = 0; mt < 4; ++mt)
      #pragma unroll
      for (int nt = 0; nt < 4; ++nt) {
        acc[mt][nt] = __builtin_amdgcn_mfma_f32_16x16x32_bf16(a[mt], bh[nt], acc[mt][nt], 0, 0, 0);
        acc[mt][nt] = __builtin_amdgcn_mfma_f32_16x16x32_bf16(a[mt], bl[nt], acc[mt][nt], 0, 0, 0);
      }
    __syncthreads();
  }

  #pragma unroll
  for (int mt = 0; mt < 4; ++mt) {
    #pragma unroll
    for (int j = 0; j < 4; ++j) {
      int m = bm * BM + wr * 64 + mt * 16 + (lane >> 4) * 4 + j;  // gate-row 0..2047
      int gate = m >> 9;
      int u    = m & 511;
      float bv = bias[m];
      #pragma unroll
      for (int nt = 0; nt < 4; ++nt) {
        int n = bn * BN + wc * 64 + nt * 16 + (lane & 15);
        int t = n >> 6, b = n & 63;
        pre[(((long)t * 512 + u) * 64 + b) * 4 + gate] = f2bf(acc[mt][nt][j] + bv);
      }
    }
  }
}

// ---------- kernel 4: persistent recurrence, self-publishing h ----------
// 128 blocks x 256 threads. Quad q = blockIdx>>5 owns batches [q*16,+16);
// block ublk = blockIdx&31 owns units [ublk*16,+16). The 4 waves of a block
// SPLIT K: wave w covers k in [w*128, +128) and computes partial sums for all
// 4 unit-tiles; partials are reduced + gate-transposed through LDS (1 barrier).
//
// h words are SELF-PUBLISHING: u32 = (bf16(h)<<16) | step_tag. A dword store
// is single-copy atomic, so the tag validates its own payload — no flags, no
// vmcnt drain, no publish barrier, ONE MALL round-trip per step. Write-after-
// read hazard is closed by the block barrier: overwriting phase t&1 (step t+2
// store) requires passing barrier(t+1), which requires every wave to have
// finished reading phase t&1. hbuf is memset per launch (tag replay aliasing).
__global__ __launch_bounds__(256, 1) void k_lstm(
    const unsigned short* __restrict__ pre,   // [S][512][64][4] bf16
    const unsigned short* __restrict__ WhhB,  // [2048][512] bf16
    unsigned* __restrict__ hbuf,              // [2][64 b][512 u] u32 (h|tag)
    float* __restrict__ out)                  // [S*B*H | h_f | c_f]
{
  __shared__ float part[2][4][4][256];  // [phase][srcwave][tile][lane*4+j] 32KB

  const int tid  = threadIdx.x;
  const int lane = tid & 63;
  const int wave = tid >> 6;          // 0..3 = K-span index
  const int q    = blockIdx.x >> 5;   // batch quad
  const int ublk = blockIdx.x & 31;   // unit block

  // --- B-fragments [tau][ks]: 8 bf16 each; 64 VGPRs total, pinned ---
  unsigned long long bq[32];
  {
    int n  = lane & 15;
    int kb = (lane >> 4) * 8;
    #pragma unroll
    for (int tau = 0; tau < 4; ++tau) {
      long r = (long)((n >> 2) * 512 + ublk * 16 + tau * 4 + (n & 3)) * 512;
      const unsigned long long* wp = (const unsigned long long*)(WhhB + r);
      #pragma unroll
      for (int ks = 0; ks < 4; ++ks) {
        int e = (wave * 128 + ks * 32 + kb) >> 2;
        bq[(tau * 4 + ks) * 2]     = wp[e];
        bq[(tau * 4 + ks) * 2 + 1] = wp[e + 1];
      }
    }
    #pragma unroll
    for (int i = 0; i < 32; ++i) asm volatile("" : "+v"(bq[i]));
  }

  // cell assignment: cu = tid&15 (unit), cb = tid>>4 (batch)
  const int cu   = tid & 15;
  const int cb   = tid >> 4;
  const int b_g  = q * 16 + cb;
  const int u_g  = ublk * 16 + cu;
  const int tauc = cu >> 2;           // == wave (cell's tile)
  const int duc  = cu & 3;

  // A-fragment addressing (per-wave K-span)
  const int arow = q * 16 + (lane & 15);
  const unsigned kbase = (unsigned)(arow * HID + wave * 128 + (lane >> 4) * 8);

  float cst = 0.f;

  #pragma unroll 1
  for (int t = 0; t < S_LEN; ++t) {
    // x-gates (8B, i/f/g/o contiguous) — issue early, hides under poll
    ushort4 pv = *(const ushort4*)(pre + (((long)t * 512 + u_g) * 64 + b_g) * 4);

    f32x4 acc[4];
    #pragma unroll
    for (int i = 0; i < 4; ++i) acc[i] = (f32x4){0.f, 0.f, 0.f, 0.f};

    if (t > 0) {
      const unsigned* hb = hbuf + (t & 1) * (BATCH * HID);
      const unsigned tagexp = (unsigned)t & 0xffffu;
      unsigned aw[32];
      // poll-on-data: re-issue loads until all 32 tags match this step
      while (true) {
        #pragma unroll
        for (int ks = 0; ks < 4; ++ks)
          #pragma unroll
          for (int j = 0; j < 8; ++j)
            aw[ks * 8 + j] = __hip_atomic_load(hb + kbase + ks * 32 + j,
                                               __ATOMIC_RELAXED,
                                               __HIP_MEMORY_SCOPE_AGENT);
        unsigned bad = 0;
        #pragma unroll
        for (int i = 0; i < 32; ++i) bad |= (aw[i] ^ tagexp) & 0xffffu;
        if (__all(bad == 0)) break;
      }
      // pack hi16 halves -> bf16 pair dwords, then MFMA (4 indep acc chains)
      short8v a[4];
      #pragma unroll
      for (int ks = 0; ks < 4; ++ks) {
        union { unsigned d[4]; short8v v; } ua;
        #pragma unroll
        for (int j = 0; j < 4; ++j)
          ua.d[j] = (aw[ks * 8 + 2 * j] >> 16) | (aw[ks * 8 + 2 * j + 1] & 0xffff0000u);
        a[ks] = ua.v;
      }
      #pragma unroll
      for (int tau = 0; tau < 4; ++tau) {
        #pragma unroll
        for (int ks = 0; ks < 4; ++ks) {
          union { unsigned long long qq[2]; short8v v; } ub_;
          ub_.qq[0] = bq[(tau * 4 + ks) * 2];
          ub_.qq[1] = bq[(tau * 4 + ks) * 2 + 1];
          acc[tau] = __builtin_amdgcn_mfma_f32_16x16x32_bf16(a[ks], ub_.v, acc[tau], 0, 0, 0);
        }
      }
    }

    // write K-partials for all 4 tiles; one barrier; read + reduce + transpose
    #pragma unroll
    for (int tau = 0; tau < 4; ++tau)
      *(f32x4*)&part[t & 1][wave][tau][lane * 4] = acc[tau];
    __syncthreads();

    float zg4[4];
    #pragma unroll
    for (int G = 0; G < 4; ++G) {
      int li = ((cb >> 2) * 16 + G * 4 + duc) * 4 + (cb & 3);
      float s = part[t & 1][0][tauc][li] + part[t & 1][1][tauc][li]
              + part[t & 1][2][tauc][li] + part[t & 1][3][tauc][li];
      zg4[G] = s;
    }

    // cell update (one cell per thread)
    float zi = zg4[0] + bf2f(pv.x);
    float zf = zg4[1] + bf2f(pv.y);
    float zg = zg4[2] + bf2f(pv.z);
    float zo = zg4[3] + bf2f(pv.w);
    float ii = 1.f / (1.f + __expf(-zi));
    float ff = 1.f / (1.f + __expf(-zf));
    float e1 = __expf(2.f * fminf(zg, 15.f));
    float gg = (e1 - 1.f) / (e1 + 1.f);
    float oo = 1.f / (1.f + __expf(-zo));
    float cn = ff * cst + ii * gg;
    float e2 = __expf(2.f * fminf(cn, 15.f));
    float tc = (e2 - 1.f) / (e2 + 1.f);
    float hv = oo * tc;
    cst = cn;

    // self-publishing h store: payload + tag in one atomic dword
    unsigned hw = ((unsigned)f2bf(hv) << 16) | ((unsigned)(t + 1) & 0xffffu);
    __hip_atomic_store(hbuf + ((t + 1) & 1) * (BATCH * HID) + b_g * HID + u_g,
                       hw, __ATOMIC_RELAXED, __HIP_MEMORY_SCOPE_AGENT);

    // out stores off the critical path (coalesced over cu)
    out[(long)t * (BATCH * HID) + (long)b_g * HID + u_g] = hv;
    if (t == S_LEN - 1) {
      long fb = (long)S_LEN * (BATCH * HID);
      out[fb + (long)b_g * HID + u_g] = hv;
      out[fb + BATCH * HID + (long)b_g * HID + u_g] = cn;
    }
  }
}

extern "C" void kernel_launch(void* const* d_in, const int* in_sizes, int n_in,
                              void* d_out, int out_size, void* d_ws, size_t ws_size,
                              hipStream_t stream) {
  const float* x   = (const float*)d_in[0];
  const float* Wih = (const float*)d_in[1];
  const float* Whh = (const float*)d_in[2];
  const float* bih = (const float*)d_in[3];
  const float* bhh = (const float*)d_in[4];
  float* out = (float*)d_out;

  char* ws = (char*)d_ws;
  size_t off = 0;
  auto alloc = [&](size_t bytes) -> char* {
    char* p = ws + off;
    off += (bytes + 255) & ~(size_t)255;
    return p;
  };
  unsigned short* xhi  = (unsigned short*)alloc((size_t)S_LEN * BATCH * DIN * 2);
  unsigned short* xlo  = (unsigned short*)alloc((size_t)S_LEN * BATCH * DIN * 2);
  unsigned short* preb = (unsigned short*)alloc((size_t)S_LEN * GATES * BATCH * 2);
  unsigned short* WihB = (unsigned short*)alloc((size_t)GATES * DIN * 2);
  unsigned short* WhhB = (unsigned short*)alloc((size_t)GATES * DIN * 2);
  float*          bias = (float*)alloc((size_t)GATES * 4);
  unsigned*       hbuf = (unsigned*)alloc((size_t)2 * BATCH * HID * 4);  // 256KB

  // tags must be cleared every launch (replay would alias step tags)
  hipMemsetAsync(hbuf, 0, (size_t)2 * BATCH * HID * 4, stream);
  k_split_x<<<8192, 256, 0, stream>>>(x, xhi, xlo);
  k_prep_w<<<4096, 256, 0, stream>>>(Wih, Whh, bih, bhh, WihB, WhhB, bias);
  k_gemm_pre<<<16384, 256, 0, stream>>>(WihB, xhi, xlo, bias, preb);
  k_lstm<<<128, 256, 0, stream>>>(preb, WhhB, hbuf, out);
}